// Round 6
// baseline (283.367 us; speedup 1.0000x reference)
//
#include <hip/hip_runtime.h>
#include <hip/hip_bf16.h>

#define HW_ 36864
#define W_ 192
#define H_ 192
#define NPIX_ 73728
#define TWO_PI_F 6.283185307179586f

typedef __attribute__((ext_vector_type(8))) short bfrag;
typedef __attribute__((ext_vector_type(4))) float f4;

__device__ __constant__ float DT_G[12] = {
    1.0f, 2.154434690031884f, 4.641588833612779f, 10.0f,
    21.54434690031884f, 46.41588833612779f, 100.0f, 215.4434690031884f,
    464.1588833612779f, 1000.0f, 2154.434690031884f, 4641.588833612779f};

__device__ __forceinline__ unsigned short f2bf(float f) {
    __hip_bfloat16 h = __float2bfloat16(f);
    unsigned short u;
    __builtin_memcpy(&u, &h, 2);
    return u;
}

struct __align__(16) Smem {
    union {
        unsigned short A[7680];  // 10 tiles x 768 u16: [0..1]=xin(32px), [2..9]=wrp(128 rows)
        float outt[4][32 * 33];  // per-wave out staging, 32 rows x (32+1 pad)
    } u;
    float wl[864];    // conv weights
    float pbl[192];   // window position bias [v][c]
    int bidx[128];    // per (pixel,v) gather index within a y-plane
    float cpart[4][32];
    float frs[32];    // per-pixel frac
};

// A-frag u16 index for (tile, row m, k):
//   ks-block (k>>5)*512, then lane = m + 16*((k>>3)&3), elem j = k&7
__device__ __forceinline__ int a_idx(int tile, int m, int k) {
    return tile * 768 + ((k >> 5) << 9) + (((k >> 3) & 3) << 7) + (m << 3) + (k & 7);
}

// B fragment from global f32 weights w[k][128]; k>=48 -> 0
__device__ __forceinline__ bfrag loadB(const float* __restrict__ w, int h, int ks,
                                       int lq, int lg) {
    int nn = (h << 4) + lq;
    int k0 = (ks << 5) + (lg << 3);
    bfrag r;
#pragma unroll
    for (int j = 0; j < 8; ++j) {
        int k = k0 + j;
        float f = (k < 48) ? w[k * 128 + nn] : 0.0f;
        r[j] = (short)f2bf(f);
    }
    return r;
}

__global__ __launch_bounds__(256, 7) void fused_kernel(
    const float* __restrict__ y, const float* __restrict__ x,
    const float* __restrict__ cw, const float* __restrict__ cb,
    const float* __restrict__ qw, const float* __restrict__ qb,
    const float* __restrict__ kw, const float* __restrict__ kb,
    const float* __restrict__ vw, const float* __restrict__ vb,
    float* __restrict__ out) {
    __shared__ Smem sm;
    int tid = threadIdx.x;
    int pix0 = blockIdx.x * 32;
    int n = pix0 / HW_;
    int rem0 = pix0 - n * HW_;
    int row0 = rem0 / W_, col0 = rem0 - row0 * W_; // all 32 px share row0

    // ---- P1: conv weights + window position bias ----
    for (int i = tid; i < 864; i += 256) sm.wl[i] = cw[i];
    if (tid < 192) {
        int v = tid / 48, c = tid - (tid / 48) * 48;
        int iy = v >> 1, ix = v & 1;
        int cc = (c < 24) ? c : c - 24;
        int sel = (c < 24) ? iy : ix;
        float e = sel ? (TWO_PI_F / (1.0f + 1e-6f)) : 0.0f;
        float arg = e / DT_G[cc >> 1];
        sm.pbl[v * 48 + c] = (cc & 1) ? cosf(arg) : sinf(arg);
    }
    __syncthreads();

    // ---- P2: 3x3 conv, lanes = consecutive pixels (coalesced) ----
    {
        int px = tid & 31, sub = tid >> 5; // 8 subs x 12 channels
        int col = col0 + px;
        float acc = 0.0f;
#pragma unroll 4
        for (int icl = 0; icl < 12; ++icl) {
            int ic = sub * 12 + icl;
            const float* src = (ic < 48) ? y : x;
            int c = (ic < 48) ? ic : ic - 48;
            size_t base = (size_t)(n * 48 + c) * HW_;
#pragma unroll
            for (int ky = 0; ky < 3; ++ky) {
                int r = row0 + ky - 1;
                if ((unsigned)r < (unsigned)H_) { // uniform per block
                    size_t rb = base + (size_t)r * W_;
#pragma unroll
                    for (int kx = 0; kx < 3; ++kx) {
                        int cc = col + kx - 1;
                        if ((unsigned)cc < (unsigned)W_)
                            acc += src[rb + cc] * sm.wl[ic * 9 + ky * 3 + kx];
                    }
                }
            }
        }
        acc += __shfl_xor(acc, 32); // fold the wave's two subs
        int lane = tid & 63;
        if (lane < 32) sm.cpart[tid >> 6][lane] = acc;
    }
    __syncthreads();

    // ---- P2b: per-pixel offset -> frac + 4 gather indices ----
    if (tid < 32) {
        float s = sm.cpart[0][tid] + sm.cpart[1][tid] + sm.cpart[2][tid] + sm.cpart[3][tid];
        float o = (s + cb[0]) * (2.0f / (float)W_);
        int col = col0 + tid;
        float gx = (float)col + o;
        float fx = floorf(gx);
        sm.frs[tid] = gx - fx;
#pragma unroll
        for (int v = 0; v < 4; ++v) {
            int rr = (int)fminf(fmaxf((float)(row0 + (v >> 1)), 0.0f), 191.0f);
            int cc = (int)fminf(fmaxf(fx + (float)(v & 1), 0.0f), 191.0f);
            sm.bidx[tid * 4 + v] = rr * W_ + cc;
        }
    }
    __syncthreads();

    // ---- P3: stage A operands (bf16 frag order, channel pairs -> b32 writes) ----
    // xin: 32px x 48c (x + point-PE, sincos inline: one angle per channel pair)
    for (int e = tid; e < 768; e += 256) {
        int cp = e >> 5, p = e & 31;
        int c0 = cp * 2;
        int rem = rem0 + p;
        float v0 = x[(size_t)(n * 48 + c0) * HW_ + rem];
        float v1 = x[(size_t)(n * 48 + c0 + 1) * HW_ + rem];
        float pe0 = 0.0f, pe1 = 1.0f;
        if (c0 >= 24) {
            float arg = sm.frs[p] * (TWO_PI_F / (2.0f + 1e-6f)) / DT_G[cp - 12];
            __sincosf(arg, &pe0, &pe1);
        }
        unsigned int pk = (unsigned int)f2bf(v0 + pe0) | ((unsigned int)f2bf(v1 + pe1) << 16);
        ((unsigned int*)sm.u.A)[a_idx(p >> 4, p & 15, c0) >> 1] = pk;
    }
    // wrp: 128 rows (px*4+v) x 48c (gathered y + window bias)
    for (int e = tid; e < 3072; e += 256) {
        int cp = e >> 7, r = e & 127;
        int c0 = cp * 2, v = r & 3;
        size_t b0 = (size_t)(n * 48 + c0) * HW_ + sm.bidx[r];
        float v0 = y[b0] + sm.pbl[v * 48 + c0];
        float v1 = y[b0 + HW_] + sm.pbl[v * 48 + c0 + 1];
        unsigned int pk = (unsigned int)f2bf(v0) | ((unsigned int)f2bf(v1) << 16);
        ((unsigned int*)sm.u.A)[a_idx(2 + (r >> 4), r & 15, c0) >> 1] = pk;
    }
    __syncthreads();

    // ---- P4: load A frags, barrier (outt aliases A), MFMA + attention ----
    int lane = tid & 63, wid = tid >> 6;
    int lq = lane & 15, lg = lane >> 4;
    bfrag zf = {};

    bfrag qA[2][2], wA[8][2];
#pragma unroll
    for (int t = 0; t < 2; ++t) {
        qA[t][0] = *(const bfrag*)&sm.u.A[t * 768 + lane * 8];
        bfrag f = *(const bfrag*)&sm.u.A[t * 768 + 512 + (lane & 31) * 8];
        qA[t][1] = (lg < 2) ? f : zf; // K pad 48->64 in registers
    }
#pragma unroll
    for (int t = 0; t < 8; ++t) {
        wA[t][0] = *(const bfrag*)&sm.u.A[(2 + t) * 768 + lane * 8];
        bfrag f = *(const bfrag*)&sm.u.A[(2 + t) * 768 + 512 + (lane & 31) * 8];
        wA[t][1] = (lg < 2) ? f : zf;
    }
    __syncthreads(); // all A reads done; outt may now alias A

    float* ow = sm.u.outt[wid];
#pragma unroll
    for (int hh = 0; hh < 2; ++hh) {
        int h = wid * 2 + hh;
        float qbv = qb[(h << 4) + lq];
        float kbv = kb[(h << 4) + lq];
        float vbv = vb[(h << 4) + lq];

        bfrag qB0 = loadB(qw, h, 0, lq, lg), qB1 = loadB(qw, h, 1, lq, lg);
        f4 qacc[2];
#pragma unroll
        for (int t = 0; t < 2; ++t) {
            f4 a = {qbv, qbv, qbv, qbv};
            a = __builtin_amdgcn_mfma_f32_16x16x32_bf16(qA[t][0], qB0, a, 0, 0, 0);
            a = __builtin_amdgcn_mfma_f32_16x16x32_bf16(qA[t][1], qB1, a, 0, 0, 0);
            qacc[t] = a;
        }
        bfrag kB0 = loadB(kw, h, 0, lq, lg), kB1 = loadB(kw, h, 1, lq, lg);
        bfrag vB0 = loadB(vw, h, 0, lq, lg), vB1 = loadB(vw, h, 1, lq, lg);

#pragma unroll
        for (int m = 0; m < 8; ++m) {
            f4 ka = {kbv, kbv, kbv, kbv};
            ka = __builtin_amdgcn_mfma_f32_16x16x32_bf16(wA[m][0], kB0, ka, 0, 0, 0);
            ka = __builtin_amdgcn_mfma_f32_16x16x32_bf16(wA[m][1], kB1, ka, 0, 0, 0);
            f4 va = {vbv, vbv, vbv, vbv};
            va = __builtin_amdgcn_mfma_f32_16x16x32_bf16(wA[m][0], vB0, va, 0, 0, 0);
            va = __builtin_amdgcn_mfma_f32_16x16x32_bf16(wA[m][1], vB1, va, 0, 0, 0);

            // q broadcast: pixel p=4m+lg is in qacc[m>>2], reg lg, lane (m&3)*16+lq
            int src = ((m & 3) << 4) | lq;
            f4 qa = qacc[m >> 2];
            float t0 = __shfl(qa.x, src), t1 = __shfl(qa.y, src);
            float t2 = __shfl(qa.z, src), t3 = __shfl(qa.w, src);
            float qv = (lg == 0) ? t0 : (lg == 1) ? t1 : (lg == 2) ? t2 : t3;
            qv *= 0.25f; // HEAD_DIM^-0.5

            float s0 = qv * ka.x, s1 = qv * ka.y, s2 = qv * ka.z, s3 = qv * ka.w;
#pragma unroll
            for (int msk = 1; msk < 16; msk <<= 1) {
                s0 += __shfl_xor(s0, msk);
                s1 += __shfl_xor(s1, msk);
                s2 += __shfl_xor(s2, msk);
                s3 += __shfl_xor(s3, msk);
            }
            float mx = fmaxf(fmaxf(s0, s1), fmaxf(s2, s3));
            float e0 = __expf(s0 - mx), e1 = __expf(s1 - mx);
            float e2 = __expf(s2 - mx), e3 = __expf(s3 - mx);
            float rden = 1.0f / (e0 + e1 + e2 + e3);
            float o = (e0 * va.x + e1 * va.y + e2 * va.z + e3 * va.w) * rden;
            ow[(hh * 16 + lq) * 33 + (m << 2) + lg] = o;
        }
    }

    // ---- P5: per-wave coalesced flush (full 128B lines) ----
    {
        int r = lane >> 1, half = lane & 1; // local row, 16-float half
        int ch = wid * 32 + r;
        const float* sp = &ow[r * 33 + half * 16];
        float4* dst = (float4*)(out + (size_t)(n * 128 + ch) * HW_ + rem0 + half * 16);
#pragma unroll
        for (int i = 0; i < 4; ++i)
            dst[i] = make_float4(sp[4 * i], sp[4 * i + 1], sp[4 * i + 2], sp[4 * i + 3]);
    }
}

extern "C" void kernel_launch(void* const* d_in, const int* in_sizes, int n_in,
                              void* d_out, int out_size, void* d_ws, size_t ws_size,
                              hipStream_t stream) {
    hipLaunchKernelGGL(fused_kernel, dim3(NPIX_ / 32), dim3(256), 0, stream,
                       (const float*)d_in[0], (const float*)d_in[1],
                       (const float*)d_in[2], (const float*)d_in[3],
                       (const float*)d_in[4], (const float*)d_in[5],
                       (const float*)d_in[6], (const float*)d_in[7],
                       (const float*)d_in[8], (const float*)d_in[9],
                       (float*)d_out);
}

// Round 7
// 281.650 us; speedup vs baseline: 1.0061x; 1.0061x over previous
//
#include <hip/hip_runtime.h>
#include <hip/hip_bf16.h>

#define HW_ 36864
#define W_ 192
#define H_ 192
#define NPIX_ 73728
#define TWO_PI_F 6.283185307179586f

typedef __attribute__((ext_vector_type(8))) short bfrag;
typedef __attribute__((ext_vector_type(4))) float f4;

__device__ __constant__ float DT_G[12] = {
    1.0f, 2.154434690031884f, 4.641588833612779f, 10.0f,
    21.54434690031884f, 46.41588833612779f, 100.0f, 215.4434690031884f,
    464.1588833612779f, 1000.0f, 2154.434690031884f, 4641.588833612779f};

__device__ __forceinline__ unsigned short f2bf(float f) {
    __hip_bfloat16 h = __float2bfloat16(f);
    unsigned short u;
    __builtin_memcpy(&u, &h, 2);
    return u;
}

struct __align__(16) Smem {
    union {
        unsigned short A[7680];  // 10 tiles x 768 u16: [0..1]=xin(32px), [2..9]=wrp(128 rows)
        float outt[4][32 * 33];  // per-wave out staging, 32 rows x (32+1 pad)
    } u;
    float wl[864];    // conv weights
    float pbl[192];   // window position bias [v][c]
    int bidx[128];    // per (pixel,v) gather index within a y-plane
    float cpart[4][32];
    float frs[32];    // per-pixel frac
};

// A-frag u16 index for (tile, row m, k):
//   ks-block (k>>5)*512, then lane = m + 16*((k>>3)&3), elem j = k&7
__device__ __forceinline__ int a_idx(int tile, int m, int k) {
    return tile * 768 + ((k >> 5) << 9) + (((k >> 3) & 3) << 7) + (m << 3) + (k & 7);
}

// B fragment from global f32 weights w[k][128]; k>=48 -> 0
__device__ __forceinline__ bfrag loadB(const float* __restrict__ w, int h, int ks,
                                       int lq, int lg) {
    int nn = (h << 4) + lq;
    int k0 = (ks << 5) + (lg << 3);
    bfrag r;
#pragma unroll
    for (int j = 0; j < 8; ++j) {
        int k = k0 + j;
        float f = (k < 48) ? w[k * 128 + nn] : 0.0f;
        r[j] = (short)f2bf(f);
    }
    return r;
}

__global__ __launch_bounds__(256, 7) void fused_kernel(
    const float* __restrict__ y, const float* __restrict__ x,
    const float* __restrict__ cw, const float* __restrict__ cb,
    const float* __restrict__ qw, const float* __restrict__ qb,
    const float* __restrict__ kw, const float* __restrict__ kb,
    const float* __restrict__ vw, const float* __restrict__ vb,
    float* __restrict__ out) {
    __shared__ Smem sm;
    int tid = threadIdx.x;
    int pix0 = blockIdx.x * 32;
    int n = pix0 / HW_;
    int rem0 = pix0 - n * HW_;
    int row0 = rem0 / W_, col0 = rem0 - row0 * W_; // all 32 px share row0

    // ---- P1: conv weights + window position bias ----
    for (int i = tid; i < 864; i += 256) sm.wl[i] = cw[i];
    if (tid < 192) {
        int v = tid / 48, c = tid - (tid / 48) * 48;
        int iy = v >> 1, ix = v & 1;
        int cc = (c < 24) ? c : c - 24;
        int sel = (c < 24) ? iy : ix;
        float e = sel ? (TWO_PI_F / (1.0f + 1e-6f)) : 0.0f;
        float arg = e / DT_G[cc >> 1];
        sm.pbl[v * 48 + c] = (cc & 1) ? cosf(arg) : sinf(arg);
    }
    __syncthreads();

    // ---- P2: 3x3 conv, lanes = consecutive pixels (coalesced) ----
    {
        int px = tid & 31, sub = tid >> 5; // 8 subs x 12 channels
        int col = col0 + px;
        float acc = 0.0f;
#pragma unroll 4
        for (int icl = 0; icl < 12; ++icl) {
            int ic = sub * 12 + icl;
            const float* src = (ic < 48) ? y : x;
            int c = (ic < 48) ? ic : ic - 48;
            size_t base = (size_t)(n * 48 + c) * HW_;
#pragma unroll
            for (int ky = 0; ky < 3; ++ky) {
                int r = row0 + ky - 1;
                if ((unsigned)r < (unsigned)H_) { // uniform per block
                    size_t rb = base + (size_t)r * W_;
#pragma unroll
                    for (int kx = 0; kx < 3; ++kx) {
                        int cc = col + kx - 1;
                        if ((unsigned)cc < (unsigned)W_)
                            acc += src[rb + cc] * sm.wl[ic * 9 + ky * 3 + kx];
                    }
                }
            }
        }
        acc += __shfl_xor(acc, 32); // fold the wave's two subs
        int lane = tid & 63;
        if (lane < 32) sm.cpart[tid >> 6][lane] = acc;
    }
    __syncthreads();

    // ---- P2b: per-pixel offset -> frac + 4 gather indices ----
    if (tid < 32) {
        float s = sm.cpart[0][tid] + sm.cpart[1][tid] + sm.cpart[2][tid] + sm.cpart[3][tid];
        float o = (s + cb[0]) * (2.0f / (float)W_);
        int col = col0 + tid;
        float gx = (float)col + o;
        float fx = floorf(gx);
        sm.frs[tid] = gx - fx;
#pragma unroll
        for (int v = 0; v < 4; ++v) {
            int rr = (int)fminf(fmaxf((float)(row0 + (v >> 1)), 0.0f), 191.0f);
            int cc = (int)fminf(fmaxf(fx + (float)(v & 1), 0.0f), 191.0f);
            sm.bidx[tid * 4 + v] = rr * W_ + cc;
        }
    }
    __syncthreads();

    // ---- P3: stage A operands (bf16 frag order, channel pairs -> b32 writes) ----
    // xin: 32px x 48c (x + point-PE, sincos inline: one angle per channel pair)
    for (int e = tid; e < 768; e += 256) {
        int cp = e >> 5, p = e & 31;
        int c0 = cp * 2;
        int rem = rem0 + p;
        float v0 = x[(size_t)(n * 48 + c0) * HW_ + rem];
        float v1 = x[(size_t)(n * 48 + c0 + 1) * HW_ + rem];
        float pe0 = 0.0f, pe1 = 1.0f;
        if (c0 >= 24) {
            float arg = sm.frs[p] * (TWO_PI_F / (2.0f + 1e-6f)) / DT_G[cp - 12];
            __sincosf(arg, &pe0, &pe1);
        }
        unsigned int pk = (unsigned int)f2bf(v0 + pe0) | ((unsigned int)f2bf(v1 + pe1) << 16);
        ((unsigned int*)sm.u.A)[a_idx(p >> 4, p & 15, c0) >> 1] = pk;
    }
    // wrp: 128 rows (px*4+v) x 48c (gathered y + window bias)
    for (int e = tid; e < 3072; e += 256) {
        int cp = e >> 7, r = e & 127;
        int c0 = cp * 2, v = r & 3;
        size_t b0 = (size_t)(n * 48 + c0) * HW_ + sm.bidx[r];
        float v0 = y[b0] + sm.pbl[v * 48 + c0];
        float v1 = y[b0 + HW_] + sm.pbl[v * 48 + c0 + 1];
        unsigned int pk = (unsigned int)f2bf(v0) | ((unsigned int)f2bf(v1) << 16);
        ((unsigned int*)sm.u.A)[a_idx(2 + (r >> 4), r & 15, c0) >> 1] = pk;
    }
    __syncthreads();

    // ---- P4: load A frags, barrier (outt aliases A), MFMA + attention ----
    int lane = tid & 63, wid = tid >> 6;
    int lq = lane & 15, lg = lane >> 4;
    bfrag zf = {};

    bfrag qA[2][2], wA[8][2];
#pragma unroll
    for (int t = 0; t < 2; ++t) {
        qA[t][0] = *(const bfrag*)&sm.u.A[t * 768 + lane * 8];
        bfrag f = *(const bfrag*)&sm.u.A[t * 768 + 512 + (lane & 31) * 8];
        qA[t][1] = (lg < 2) ? f : zf; // K pad 48->64 in registers
    }
#pragma unroll
    for (int t = 0; t < 8; ++t) {
        wA[t][0] = *(const bfrag*)&sm.u.A[(2 + t) * 768 + lane * 8];
        bfrag f = *(const bfrag*)&sm.u.A[(2 + t) * 768 + 512 + (lane & 31) * 8];
        wA[t][1] = (lg < 2) ? f : zf;
    }
    __syncthreads(); // all A reads done; outt may now alias A

    float* ow = sm.u.outt[wid];
#pragma unroll
    for (int hh = 0; hh < 2; ++hh) {
        int h = wid * 2 + hh;
        float qbv = qb[(h << 4) + lq];
        float kbv = kb[(h << 4) + lq];
        float vbv = vb[(h << 4) + lq];

        bfrag qB0 = loadB(qw, h, 0, lq, lg), qB1 = loadB(qw, h, 1, lq, lg);
        f4 qacc[2];
#pragma unroll
        for (int t = 0; t < 2; ++t) {
            f4 a = {qbv, qbv, qbv, qbv};
            a = __builtin_amdgcn_mfma_f32_16x16x32_bf16(qA[t][0], qB0, a, 0, 0, 0);
            a = __builtin_amdgcn_mfma_f32_16x16x32_bf16(qA[t][1], qB1, a, 0, 0, 0);
            qacc[t] = a;
        }
        bfrag kB0 = loadB(kw, h, 0, lq, lg), kB1 = loadB(kw, h, 1, lq, lg);
        bfrag vB0 = loadB(vw, h, 0, lq, lg), vB1 = loadB(vw, h, 1, lq, lg);

#pragma unroll
        for (int m = 0; m < 8; ++m) {
            f4 ka = {kbv, kbv, kbv, kbv};
            ka = __builtin_amdgcn_mfma_f32_16x16x32_bf16(wA[m][0], kB0, ka, 0, 0, 0);
            ka = __builtin_amdgcn_mfma_f32_16x16x32_bf16(wA[m][1], kB1, ka, 0, 0, 0);
            f4 va = {vbv, vbv, vbv, vbv};
            va = __builtin_amdgcn_mfma_f32_16x16x32_bf16(wA[m][0], vB0, va, 0, 0, 0);
            va = __builtin_amdgcn_mfma_f32_16x16x32_bf16(wA[m][1], vB1, va, 0, 0, 0);

            // q broadcast: pixel p=4m+lg is in qacc[m>>2], reg lg, lane (m&3)*16+lq
            int src = ((m & 3) << 4) | lq;
            f4 qa = qacc[m >> 2];
            float t0 = __shfl(qa.x, src), t1 = __shfl(qa.y, src);
            float t2 = __shfl(qa.z, src), t3 = __shfl(qa.w, src);
            float qv = (lg == 0) ? t0 : (lg == 1) ? t1 : (lg == 2) ? t2 : t3;
            qv *= 0.25f; // HEAD_DIM^-0.5

            float s0 = qv * ka.x, s1 = qv * ka.y, s2 = qv * ka.z, s3 = qv * ka.w;
#pragma unroll
            for (int msk = 1; msk < 16; msk <<= 1) {
                s0 += __shfl_xor(s0, msk);
                s1 += __shfl_xor(s1, msk);
                s2 += __shfl_xor(s2, msk);
                s3 += __shfl_xor(s3, msk);
            }
            float mx = fmaxf(fmaxf(s0, s1), fmaxf(s2, s3));
            float e0 = __expf(s0 - mx), e1 = __expf(s1 - mx);
            float e2 = __expf(s2 - mx), e3 = __expf(s3 - mx);
            float rden = 1.0f / (e0 + e1 + e2 + e3);
            float o = (e0 * va.x + e1 * va.y + e2 * va.z + e3 * va.w) * rden;
            ow[(hh * 16 + lq) * 33 + (m << 2) + lg] = o;
        }
    }

    // ---- P5: flush — each instruction covers full 128B lines ----
    // lane L handles 16B chunk (L&7) of rows (L>>3)+8i: 8 lanes x 16B = one
    // complete line per row per instruction (no partial-line write-allocate).
    {
        int sub = lane & 7, rbase = lane >> 3;
#pragma unroll
        for (int i = 0; i < 4; ++i) {
            int r = rbase + 8 * i;
            int ch = wid * 32 + r;
            const float* sp = &ow[r * 33 + sub * 4];
            *(float4*)(out + (size_t)(n * 128 + ch) * HW_ + rem0 + sub * 4) =
                make_float4(sp[0], sp[1], sp[2], sp[3]);
        }
    }
}

extern "C" void kernel_launch(void* const* d_in, const int* in_sizes, int n_in,
                              void* d_out, int out_size, void* d_ws, size_t ws_size,
                              hipStream_t stream) {
    hipLaunchKernelGGL(fused_kernel, dim3(NPIX_ / 32), dim3(256), 0, stream,
                       (const float*)d_in[0], (const float*)d_in[1],
                       (const float*)d_in[2], (const float*)d_in[3],
                       (const float*)d_in[4], (const float*)d_in[5],
                       (const float*)d_in[6], (const float*)d_in[7],
                       (const float*)d_in[8], (const float*)d_in[9],
                       (float*)d_out);
}

// Round 8
// 270.869 us; speedup vs baseline: 1.0461x; 1.0398x over previous
//
#include <hip/hip_runtime.h>
#include <hip/hip_bf16.h>

#define HW_ 36864
#define W_ 192
#define H_ 192
#define NPIX_ 73728
#define TWO_PI_F 6.283185307179586f

typedef __attribute__((ext_vector_type(8))) short bfrag;
typedef __attribute__((ext_vector_type(4))) float f4;

__device__ __constant__ float DT_G[12] = {
    1.0f, 2.154434690031884f, 4.641588833612779f, 10.0f,
    21.54434690031884f, 46.41588833612779f, 100.0f, 215.4434690031884f,
    464.1588833612779f, 1000.0f, 2154.434690031884f, 4641.588833612779f};

__device__ __forceinline__ unsigned short f2bf(float f) {
    __hip_bfloat16 h = __float2bfloat16(f);
    unsigned short u;
    __builtin_memcpy(&u, &h, 2);
    return u;
}

struct __align__(16) Smem {
    union {
        unsigned short A[7680];  // 10 tiles x 768 u16: [0..1]=xin(32px), [2..9]=wrp(128 rows)
        float outt[4][32 * 33];  // per-wave out staging, 32 rows x (32+1 pad)
    } u;
    float wl[864];    // conv weights
    float pbl[192];   // window position bias [v][c]
    int bidx[128];    // per (pixel,v) gather index within a y-plane
    float cpart[4][32];
    float frs[32];    // per-pixel frac
};

// A-frag u16 index for (tile, row m, k):
//   ks-block (k>>5)*512, then lane = m + 16*((k>>3)&3), elem j = k&7
__device__ __forceinline__ int a_idx(int tile, int m, int k) {
    return tile * 768 + ((k >> 5) << 9) + (((k >> 3) & 3) << 7) + (m << 3) + (k & 7);
}

// B fragment from global f32 weights w[k][128]; k>=48 -> 0
__device__ __forceinline__ bfrag loadB(const float* __restrict__ w, int h, int ks,
                                       int lq, int lg) {
    int nn = (h << 4) + lq;
    int k0 = (ks << 5) + (lg << 3);
    bfrag r;
#pragma unroll
    for (int j = 0; j < 8; ++j) {
        int k = k0 + j;
        float f = (k < 48) ? w[k * 128 + nn] : 0.0f;
        r[j] = (short)f2bf(f);
    }
    return r;
}

__global__ __launch_bounds__(256, 7) void fused_kernel(
    const float* __restrict__ y, const float* __restrict__ x,
    const float* __restrict__ cw, const float* __restrict__ cb,
    const float* __restrict__ qw, const float* __restrict__ qb,
    const float* __restrict__ kw, const float* __restrict__ kb,
    const float* __restrict__ vw, const float* __restrict__ vb,
    float* __restrict__ out) {
    __shared__ Smem sm;
    int tid = threadIdx.x;
    // XCD-aware swizzle: round-robin dispatch (xcd = bx & 7) -> give each XCD
    // a contiguous 48-row band so conv-halo rows and gather windows reuse in
    // its private L2. pb unique over [0, 2304).
    int pb = ((blockIdx.x & 7) * 288) + (blockIdx.x >> 3);
    int pix0 = pb * 32;
    int n = pix0 / HW_;
    int rem0 = pix0 - n * HW_;
    int row0 = rem0 / W_, col0 = rem0 - row0 * W_; // all 32 px share row0

    // ---- P1: conv weights + window position bias ----
    for (int i = tid; i < 864; i += 256) sm.wl[i] = cw[i];
    if (tid < 192) {
        int v = tid / 48, c = tid - (tid / 48) * 48;
        int iy = v >> 1, ix = v & 1;
        int cc = (c < 24) ? c : c - 24;
        int sel = (c < 24) ? iy : ix;
        float e = sel ? (TWO_PI_F / (1.0f + 1e-6f)) : 0.0f;
        float arg = e / DT_G[cc >> 1];
        sm.pbl[v * 48 + c] = (cc & 1) ? cosf(arg) : sinf(arg);
    }
    __syncthreads();

    // ---- P2: 3x3 conv, lanes = consecutive pixels (coalesced) ----
    {
        int px = tid & 31, sub = tid >> 5; // 8 subs x 12 channels
        int col = col0 + px;
        float acc = 0.0f;
#pragma unroll 4
        for (int icl = 0; icl < 12; ++icl) {
            int ic = sub * 12 + icl;
            const float* src = (ic < 48) ? y : x;
            int c = (ic < 48) ? ic : ic - 48;
            size_t base = (size_t)(n * 48 + c) * HW_;
#pragma unroll
            for (int ky = 0; ky < 3; ++ky) {
                int r = row0 + ky - 1;
                if ((unsigned)r < (unsigned)H_) { // uniform per block
                    size_t rb = base + (size_t)r * W_;
#pragma unroll
                    for (int kx = 0; kx < 3; ++kx) {
                        int cc = col + kx - 1;
                        if ((unsigned)cc < (unsigned)W_)
                            acc += src[rb + cc] * sm.wl[ic * 9 + ky * 3 + kx];
                    }
                }
            }
        }
        acc += __shfl_xor(acc, 32); // fold the wave's two subs
        int lane = tid & 63;
        if (lane < 32) sm.cpart[tid >> 6][lane] = acc;
    }
    __syncthreads();

    // ---- P2b: per-pixel offset -> frac + 4 gather indices ----
    if (tid < 32) {
        float s = sm.cpart[0][tid] + sm.cpart[1][tid] + sm.cpart[2][tid] + sm.cpart[3][tid];
        float o = (s + cb[0]) * (2.0f / (float)W_);
        int col = col0 + tid;
        float gx = (float)col + o;
        float fx = floorf(gx);
        sm.frs[tid] = gx - fx;
#pragma unroll
        for (int v = 0; v < 4; ++v) {
            int rr = (int)fminf(fmaxf((float)(row0 + (v >> 1)), 0.0f), 191.0f);
            int cc = (int)fminf(fmaxf(fx + (float)(v & 1), 0.0f), 191.0f);
            sm.bidx[tid * 4 + v] = rr * W_ + cc;
        }
    }
    __syncthreads();

    // ---- P3: stage A operands (bf16 frag order, channel pairs -> b32 writes) ----
    // xin: 32px x 48c (x + point-PE, sincos inline: one angle per channel pair)
    for (int e = tid; e < 768; e += 256) {
        int cp = e >> 5, p = e & 31;
        int c0 = cp * 2;
        int rem = rem0 + p;
        float v0 = x[(size_t)(n * 48 + c0) * HW_ + rem];
        float v1 = x[(size_t)(n * 48 + c0 + 1) * HW_ + rem];
        float pe0 = 0.0f, pe1 = 1.0f;
        if (c0 >= 24) {
            float arg = sm.frs[p] * (TWO_PI_F / (2.0f + 1e-6f)) / DT_G[cp - 12];
            __sincosf(arg, &pe0, &pe1);
        }
        unsigned int pk = (unsigned int)f2bf(v0 + pe0) | ((unsigned int)f2bf(v1 + pe1) << 16);
        ((unsigned int*)sm.u.A)[a_idx(p >> 4, p & 15, c0) >> 1] = pk;
    }
    // wrp: 128 rows (px*4+v) x 48c (gathered y + window bias)
    for (int e = tid; e < 3072; e += 256) {
        int cp = e >> 7, r = e & 127;
        int c0 = cp * 2, v = r & 3;
        size_t b0 = (size_t)(n * 48 + c0) * HW_ + sm.bidx[r];
        float v0 = y[b0] + sm.pbl[v * 48 + c0];
        float v1 = y[b0 + HW_] + sm.pbl[v * 48 + c0 + 1];
        unsigned int pk = (unsigned int)f2bf(v0) | ((unsigned int)f2bf(v1) << 16);
        ((unsigned int*)sm.u.A)[a_idx(2 + (r >> 4), r & 15, c0) >> 1] = pk;
    }
    __syncthreads();

    // ---- P4: load A frags, barrier (outt aliases A), MFMA + attention ----
    int lane = tid & 63, wid = tid >> 6;
    int lq = lane & 15, lg = lane >> 4;
    bfrag zf = {};

    bfrag qA[2][2], wA[8][2];
#pragma unroll
    for (int t = 0; t < 2; ++t) {
        qA[t][0] = *(const bfrag*)&sm.u.A[t * 768 + lane * 8];
        bfrag f = *(const bfrag*)&sm.u.A[t * 768 + 512 + (lane & 31) * 8];
        qA[t][1] = (lg < 2) ? f : zf; // K pad 48->64 in registers
    }
#pragma unroll
    for (int t = 0; t < 8; ++t) {
        wA[t][0] = *(const bfrag*)&sm.u.A[(2 + t) * 768 + lane * 8];
        bfrag f = *(const bfrag*)&sm.u.A[(2 + t) * 768 + 512 + (lane & 31) * 8];
        wA[t][1] = (lg < 2) ? f : zf;
    }
    __syncthreads(); // all A reads done; outt may now alias A

    float* ow = sm.u.outt[wid];
#pragma unroll
    for (int hh = 0; hh < 2; ++hh) {
        int h = wid * 2 + hh;
        float qbv = qb[(h << 4) + lq];
        float kbv = kb[(h << 4) + lq];
        float vbv = vb[(h << 4) + lq];

        bfrag qB0 = loadB(qw, h, 0, lq, lg), qB1 = loadB(qw, h, 1, lq, lg);
        f4 qacc[2];
#pragma unroll
        for (int t = 0; t < 2; ++t) {
            f4 a = {qbv, qbv, qbv, qbv};
            a = __builtin_amdgcn_mfma_f32_16x16x32_bf16(qA[t][0], qB0, a, 0, 0, 0);
            a = __builtin_amdgcn_mfma_f32_16x16x32_bf16(qA[t][1], qB1, a, 0, 0, 0);
            qacc[t] = a;
        }
        bfrag kB0 = loadB(kw, h, 0, lq, lg), kB1 = loadB(kw, h, 1, lq, lg);
        bfrag vB0 = loadB(vw, h, 0, lq, lg), vB1 = loadB(vw, h, 1, lq, lg);

#pragma unroll
        for (int m = 0; m < 8; ++m) {
            f4 ka = {kbv, kbv, kbv, kbv};
            ka = __builtin_amdgcn_mfma_f32_16x16x32_bf16(wA[m][0], kB0, ka, 0, 0, 0);
            ka = __builtin_amdgcn_mfma_f32_16x16x32_bf16(wA[m][1], kB1, ka, 0, 0, 0);
            f4 va = {vbv, vbv, vbv, vbv};
            va = __builtin_amdgcn_mfma_f32_16x16x32_bf16(wA[m][0], vB0, va, 0, 0, 0);
            va = __builtin_amdgcn_mfma_f32_16x16x32_bf16(wA[m][1], vB1, va, 0, 0, 0);

            // q broadcast: pixel p=4m+lg is in qacc[m>>2], reg lg, lane (m&3)*16+lq
            int src = ((m & 3) << 4) | lq;
            f4 qa = qacc[m >> 2];
            float t0 = __shfl(qa.x, src), t1 = __shfl(qa.y, src);
            float t2 = __shfl(qa.z, src), t3 = __shfl(qa.w, src);
            float qv = (lg == 0) ? t0 : (lg == 1) ? t1 : (lg == 2) ? t2 : t3;
            qv *= 0.25f; // HEAD_DIM^-0.5

            float s0 = qv * ka.x, s1 = qv * ka.y, s2 = qv * ka.z, s3 = qv * ka.w;
#pragma unroll
            for (int msk = 1; msk < 16; msk <<= 1) {
                s0 += __shfl_xor(s0, msk);
                s1 += __shfl_xor(s1, msk);
                s2 += __shfl_xor(s2, msk);
                s3 += __shfl_xor(s3, msk);
            }
            float mx = fmaxf(fmaxf(s0, s1), fmaxf(s2, s3));
            float e0 = __expf(s0 - mx), e1 = __expf(s1 - mx);
            float e2 = __expf(s2 - mx), e3 = __expf(s3 - mx);
            float rden = 1.0f / (e0 + e1 + e2 + e3);
            float o = (e0 * va.x + e1 * va.y + e2 * va.z + e3 * va.w) * rden;
            ow[(hh * 16 + lq) * 33 + (m << 2) + lg] = o;
        }
    }

    // ---- P5: non-temporal flush, full 128B lines per instruction ----
    {
        int sub = lane & 7, rbase = lane >> 3;
#pragma unroll
        for (int i = 0; i < 4; ++i) {
            int r = rbase + 8 * i;
            int ch = wid * 32 + r;
            const float* sp = &ow[r * 33 + sub * 4];
            f4 v = {sp[0], sp[1], sp[2], sp[3]};
            __builtin_nontemporal_store(
                v, (f4*)(out + (size_t)(n * 128 + ch) * HW_ + rem0 + sub * 4));
        }
    }
}

extern "C" void kernel_launch(void* const* d_in, const int* in_sizes, int n_in,
                              void* d_out, int out_size, void* d_ws, size_t ws_size,
                              hipStream_t stream) {
    hipLaunchKernelGGL(fused_kernel, dim3(NPIX_ / 32), dim3(256), 0, stream,
                       (const float*)d_in[0], (const float*)d_in[1],
                       (const float*)d_in[2], (const float*)d_in[3],
                       (const float*)d_in[4], (const float*)d_in[5],
                       (const float*)d_in[6], (const float*)d_in[7],
                       (const float*)d_in[8], (const float*)d_in[9],
                       (float*)d_out);
}